// Round 1
// baseline (431.844 us; speedup 1.0000x reference)
//
#include <hip/hip_runtime.h>
#include <math.h>

// ---------------- types ----------------
using short8  = __attribute__((ext_vector_type(8))) short;   // 8 bf16 = 4 VGPR (MFMA A/B frag)
using floatx4 = __attribute__((ext_vector_type(4))) float;   // MFMA C/D frag
using uintx4  = __attribute__((ext_vector_type(4))) unsigned int;
using uintx2  = __attribute__((ext_vector_type(2))) unsigned int;

__device__ __forceinline__ unsigned short f2bf(float f) {
  union { float f; unsigned int u; } v; v.f = f;
  unsigned int r = v.u + 0x7FFFu + ((v.u >> 16) & 1u);  // RNE
  return (unsigned short)(r >> 16);
}

// Problem constants
#define B_  16
#define L_  4096
#define E_  128
#define F_  256
#define Y_  1000

// workspace offsets (bytes)
#define OFF_EMB 0u                // B*L*E bf16 = 16 MB, (b,l,e) row-major
#define OFF_HLF 16777216u         // B*L*F bf16 = 32 MB, (b,l,f)
#define OFF_HFL 50331648u         // B*F*L bf16 = 32 MB, (b,f,l)
#define OFF_UBF 83886080u         // 1024*256 bf16 (U zero-padded to 1024 rows)

// ---------------- K0: repack U_w -> bf16, pad Y to 1024 ----------------
__global__ __launch_bounds__(256) void k_repack_u(const float* __restrict__ Uw,
                                                  unsigned short* __restrict__ ubf) {
  int i = blockIdx.x * 256 + threadIdx.x;     // 1024*256 elements
  int y = i >> 8, f = i & 255;
  float v = (y < Y_) ? Uw[y * F_ + f] : 0.f;
  ubf[i] = f2bf(v);
}

// ---------------- K1: embedding gather fp32 -> bf16 ----------------
__global__ __launch_bounds__(256) void k_embed(const int* __restrict__ x,
                                               const float* __restrict__ ew,
                                               unsigned int* __restrict__ emb) {
  int i = blockIdx.x * 256 + threadIdx.x;     // 4,194,304 threads, 2 elems each
  int row = i >> 6;                           // (b,l) flat row, 64 pairs per row
  int e2  = i & 63;                           // pair index within row
  int idx = x[row];
  const float2* src = reinterpret_cast<const float2*>(ew + (size_t)idx * E_);
  float2 v = src[e2];
  emb[i] = (unsigned int)f2bf(v.x) | ((unsigned int)f2bf(v.y) << 16);
}

// ---------------- K2: conv1d(K=3, SAME) + bias + relu via MFMA ----------------
// grid 1024: bid = nq (f-quarter of 64) | grp(256): b, 256-row group. 4 mtiles of 64 l.
#define WT_STR 272   // 128 e * 2B + 16 pad
#define ET_STR 272
__global__ __launch_bounds__(256) void k_conv(const float* __restrict__ conv_w,
                                              const float* __restrict__ conv_b,
                                              const unsigned short* __restrict__ emb,
                                              unsigned short* __restrict__ hlf) {
  __shared__ unsigned char lds[3 * 64 * WT_STR + 66 * ET_STR];  // 52224 + 17952 = 70176
  unsigned char* wt = lds;                       // [d][fl<64][e], row stride 272
  unsigned char* et = lds + 3 * 64 * WT_STR;     // [row<66][e], row stride 272
  const int tid = threadIdx.x, bid = blockIdx.x;
  const int nq = bid & 3;            // f-quarter
  const int grp = bid >> 2;
  const int b = grp >> 4;
  const int l0g = (grp & 15) << 8;   // 256 rows per wg
  // stage W (fp32 -> bf16), layout [d][f_local][e]
  for (int u = tid; u < 64 * 128; u += 256) {
    int fl = u >> 7, e = u & 127;
    const float* src = conv_w + (((nq * 64 + fl) * E_) + e) * 3;
    #pragma unroll
    for (int k = 0; k < 3; ++k)
      *(unsigned short*)(wt + k * (64 * WT_STR) + fl * WT_STR + e * 2) = f2bf(src[k]);
  }
  __syncthreads();
  const int w = tid >> 6, lane = tid & 63, c = lane & 15, q = lane >> 4;
  for (int mt = 0; mt < 4; ++mt) {
    int l0m = l0g + (mt << 6);
    // stage Emb tile rows l0m-1 .. l0m+64 (66 rows x 256B), zero-fill OOB
    for (int s = tid; s < 66 * 16; s += 256) {
      int row = s >> 4, sg = s & 15;
      int l = l0m - 1 + row;
      uintx4 v = {0u, 0u, 0u, 0u};
      if (l >= 0 && l < L_)
        v = *(const uintx4*)((const unsigned char*)emb + ((size_t)b * L_ + l) * (E_ * 2) + sg * 16);
      *(uintx4*)(et + row * ET_STR + sg * 16) = v;
    }
    __syncthreads();
    floatx4 acc[4];
    #pragma unroll
    for (int n = 0; n < 4; ++n) acc[n] = (floatx4){0.f, 0.f, 0.f, 0.f};
    #pragma unroll
    for (int d = 0; d < 3; ++d) {
      #pragma unroll
      for (int kq = 0; kq < 4; ++kq) {
        short8 a = *(const short8*)(et + (w * 16 + c + d) * ET_STR + kq * 64 + q * 16);
        #pragma unroll
        for (int n = 0; n < 4; ++n) {
          short8 bb = *(const short8*)(wt + d * (64 * WT_STR) + (n * 16 + c) * WT_STR + kq * 64 + q * 16);
          acc[n] = __builtin_amdgcn_mfma_f32_16x16x32_bf16(a, bb, acc[n], 0, 0, 0);
        }
      }
    }
    // epilogue: bias + relu, write H (l,f) layout
    #pragma unroll
    for (int n = 0; n < 4; ++n) {
      int fg = nq * 64 + n * 16 + c;
      float bias = conv_b[fg];
      #pragma unroll
      for (int r = 0; r < 4; ++r) {
        int l = l0m + w * 16 + q * 4 + r;
        float v = acc[n][r] + bias;
        v = v > 0.f ? v : 0.f;
        hlf[((size_t)b * L_ + l) * F_ + fg] = f2bf(v);
      }
    }
    __syncthreads();
  }
}

// ---------------- K3: transpose (b,l,f) -> (b,f,l), 64x64 LDS tiles ----------------
#define TT_STR 152  // 64 l * 2B + 24 pad (8B-aligned, stride*8 != 0 mod 128B)
__global__ __launch_bounds__(256) void k_transpose(const unsigned short* __restrict__ hlf,
                                                   unsigned short* __restrict__ hfl) {
  __shared__ unsigned char t[64 * TT_STR];   // rows = l (64), cols = f (64 * 2B)
  const int tid = threadIdx.x, bid = blockIdx.x;
  const int lt = bid & 63, ft = (bid >> 6) & 3, b = bid >> 8;
  const int l0 = lt << 6, f0 = ft << 6;
  for (int s = tid; s < 1024; s += 256) {
    int row = s >> 4, sg = s & 15;  // 16 x 8B segs per l-row
    uintx2 v = *(const uintx2*)((const unsigned char*)hlf +
                (((size_t)b * L_ + l0 + row) * F_ + f0 + sg * 4) * 2);
    *(uintx2*)(t + row * TT_STR + sg * 8) = v;
  }
  __syncthreads();
  for (int s = tid; s < 1024; s += 256) {
    int frow = s >> 4, lsg = s & 15;
    unsigned int lo = (unsigned int)*(const unsigned short*)(t + (lsg * 4 + 0) * TT_STR + frow * 2)
                    | ((unsigned int)*(const unsigned short*)(t + (lsg * 4 + 1) * TT_STR + frow * 2) << 16);
    unsigned int hi = (unsigned int)*(const unsigned short*)(t + (lsg * 4 + 2) * TT_STR + frow * 2)
                    | ((unsigned int)*(const unsigned short*)(t + (lsg * 4 + 3) * TT_STR + frow * 2) << 16);
    uintx2 v; v.x = lo; v.y = hi;
    *(uintx2*)((unsigned char*)hfl + (((size_t)b * F_ + f0 + frow) * L_ + l0 + lsg * 4) * 2) = v;
  }
}

// ---------------- K4: label-wise attention (flash over L) + logits ----------------
// grid 256 = 16 b x 16 y-tiles(64); wg = 4 waves, wave owns 16 y rows.
#define HLF_STR 528   // 256 f * 2B + 16
#define HFL_STR 144   // 64 l * 2B + 16
#define P_STR   144
__global__ __launch_bounds__(256) void k_attn(const unsigned short* __restrict__ ubf,
                                              const unsigned short* __restrict__ hlf,
                                              const unsigned short* __restrict__ hfl,
                                              const float* __restrict__ fcw,
                                              const float* __restrict__ fcb,
                                              float* __restrict__ out) {
  __shared__ unsigned char lds[64 * HLF_STR + 256 * HFL_STR + 4 * 16 * P_STR]; // 79872
  unsigned char* shlf = lds;                          // [l<64][f<256]
  unsigned char* shfl = lds + 64 * HLF_STR;           // [f<256][l<64]
  unsigned char* sP   = lds + 64 * HLF_STR + 256 * HFL_STR; // per-wave [y<16][l<64]
  const int tid = threadIdx.x;
  const int w = tid >> 6, lane = tid & 63, c = lane & 15, q = lane >> 4;
  const int bid = blockIdx.x;
  // XCD swizzle: blocks on XCD x (heuristic bid%8) share batches {2x, 2x+1}
  const int xcd = bid & 7, j = bid >> 3;
  const int b = 2 * xcd + (j & 1);
  const int yt = j >> 1;
  const int yw = yt * 64 + w * 16;        // wave's y base
  // U A-fragments (K=256 -> 8 k-steps), resident in registers
  short8 uf[8];
  #pragma unroll
  for (int kq = 0; kq < 8; ++kq)
    uf[kq] = *(const short8*)((const unsigned char*)ubf + ((yw + c) * F_ + kq * 32 + q * 8) * 2);
  // ones B-frag: col 0 of B = 1.0 -> accumulates row-sums of P
  short8 ones;
  #pragma unroll
  for (int i = 0; i < 8; ++i) ones[i] = (c == 0) ? (short)0x3F80 : (short)0;
  floatx4 O[16];
  #pragma unroll
  for (int n = 0; n < 16; ++n) O[n] = (floatx4){0.f, 0.f, 0.f, 0.f};
  floatx4 La = (floatx4){0.f, 0.f, 0.f, 0.f};
  const unsigned char* hlfb = (const unsigned char*)hlf + (size_t)b * L_ * (F_ * 2);
  const unsigned char* hflb = (const unsigned char*)hfl + (size_t)b * F_ * (L_ * 2);

  for (int it = 0; it < 64; ++it) {
    const int l0 = it << 6;
    // stage H(l,f) tile: 64 rows x 512B
    for (int s = tid; s < 2048; s += 256) {
      int row = s >> 5, sg = s & 31;
      uintx4 v = *(const uintx4*)(hlfb + (size_t)(l0 + row) * (F_ * 2) + sg * 16);
      *(uintx4*)(shlf + row * HLF_STR + sg * 16) = v;
    }
    // stage H(f,l) tile: 256 rows x 128B
    for (int s = tid; s < 2048; s += 256) {
      int f = s >> 3, sg = s & 7;
      uintx4 v = *(const uintx4*)(hflb + (size_t)f * (L_ * 2) + l0 * 2 + sg * 16);
      *(uintx4*)(shfl + f * HFL_STR + sg * 16) = v;
    }
    __syncthreads();
    // GEMM1: S[16y x 64l] = U x H^T  (K = F = 256)
    floatx4 S[4];
    #pragma unroll
    for (int nt = 0; nt < 4; ++nt) S[nt] = (floatx4){0.f, 0.f, 0.f, 0.f};
    #pragma unroll
    for (int kq = 0; kq < 8; ++kq) {
      short8 a = uf[kq];
      #pragma unroll
      for (int nt = 0; nt < 4; ++nt) {
        short8 bb = *(const short8*)(shlf + (nt * 16 + c) * HLF_STR + kq * 64 + q * 16);
        S[nt] = __builtin_amdgcn_mfma_f32_16x16x32_bf16(a, bb, S[nt], 0, 0, 0);
      }
    }
    // P = exp(S) (|S| << 80: max-free softmax is safe), C-layout -> LDS (A-layout source)
    #pragma unroll
    for (int nt = 0; nt < 4; ++nt)
      #pragma unroll
      for (int r = 0; r < 4; ++r) {
        float p = __expf(S[nt][r]);
        *(unsigned short*)(sP + w * (16 * P_STR) + (q * 4 + r) * P_STR + (nt * 16 + c) * 2) = f2bf(p);
      }
    // GEMM2: O[16y x 256f] += P x H ; La += P x ones (row sums). Wave-private P: no barrier.
    #pragma unroll
    for (int kq = 0; kq < 2; ++kq) {
      short8 a2 = *(const short8*)(sP + w * (16 * P_STR) + c * P_STR + kq * 64 + q * 16);
      La = __builtin_amdgcn_mfma_f32_16x16x32_bf16(a2, ones, La, 0, 0, 0);
      #pragma unroll
      for (int nt = 0; nt < 16; ++nt) {
        short8 bb = *(const short8*)(shfl + (nt * 16 + c) * HFL_STR + kq * 64 + q * 16);
        O[nt] = __builtin_amdgcn_mfma_f32_16x16x32_bf16(a2, bb, O[nt], 0, 0, 0);
      }
    }
    __syncthreads();
  }
  // epilogue: logit[y] = (sum_f fc_w[y,f] * O[y,f]) / La[y] + fc_b[y]
  float part[4] = {0.f, 0.f, 0.f, 0.f};
  #pragma unroll
  for (int nt = 0; nt < 16; ++nt) {
    int f = nt * 16 + c;
    #pragma unroll
    for (int r = 0; r < 4; ++r) {
      int y = yw + q * 4 + r;
      float fcv = (y < Y_) ? fcw[y * F_ + f] : 0.f;
      part[r] += O[nt][r] * fcv;
    }
  }
  #pragma unroll
  for (int off = 1; off < 16; off <<= 1)
    #pragma unroll
    for (int r = 0; r < 4; ++r) part[r] += __shfl_xor(part[r], off, 64);
  if (c == 0) {
    #pragma unroll
    for (int r = 0; r < 4; ++r) {
      int y = yw + q * 4 + r;
      if (y < Y_) out[b * Y_ + y] = part[r] / La[r] + fcb[y];
    }
  }
}

// ---------------- K5: cross-entropy loss over logits ----------------
__global__ __launch_bounds__(256) void k_loss(const int* __restrict__ target, float* __restrict__ out) {
  __shared__ float red[4];
  const int tid = threadIdx.x, w = tid >> 6, lane = tid & 63;
  float loss = 0.f;
  for (int b = 0; b < B_; ++b) {
    const float* lg = out + b * Y_;
    float m = -1e30f;
    for (int i = tid; i < Y_; i += 256) m = fmaxf(m, lg[i]);
    for (int off = 1; off < 64; off <<= 1) m = fmaxf(m, __shfl_xor(m, off, 64));
    if (lane == 0) red[w] = m;
    __syncthreads();
    m = fmaxf(fmaxf(red[0], red[1]), fmaxf(red[2], red[3]));
    __syncthreads();
    float s = 0.f;
    for (int i = tid; i < Y_; i += 256) s += __expf(lg[i] - m);
    for (int off = 1; off < 64; off <<= 1) s += __shfl_xor(s, off, 64);
    if (lane == 0) red[w] = s;
    __syncthreads();
    s = red[0] + red[1] + red[2] + red[3];
    if (tid == 0) loss += -(lg[target[b]] - m - logf(s));
    __syncthreads();
  }
  if (tid == 0) out[B_ * Y_] = loss * (1.f / (float)B_);
}

// ---------------- launcher ----------------
extern "C" void kernel_launch(void* const* d_in, const int* in_sizes, int n_in,
                              void* d_out, int out_size, void* d_ws, size_t ws_size,
                              hipStream_t stream) {
  const int*   x       = (const int*)d_in[0];
  const int*   target  = (const int*)d_in[1];
  const float* embed_w = (const float*)d_in[2];
  const float* conv_w  = (const float*)d_in[3];
  const float* conv_b  = (const float*)d_in[4];
  const float* U_w     = (const float*)d_in[5];
  const float* fc_w    = (const float*)d_in[6];
  const float* fc_b    = (const float*)d_in[7];
  float* out = (float*)d_out;
  unsigned char* ws = (unsigned char*)d_ws;
  unsigned int*   emb = (unsigned int*)(ws + OFF_EMB);
  unsigned short* hlf = (unsigned short*)(ws + OFF_HLF);
  unsigned short* hfl = (unsigned short*)(ws + OFF_HFL);
  unsigned short* ubf = (unsigned short*)(ws + OFF_UBF);

  k_repack_u<<<1024, 256, 0, stream>>>(U_w, ubf);
  k_embed<<<16384, 256, 0, stream>>>(x, embed_w, emb);
  k_conv<<<1024, 256, 0, stream>>>(conv_w, conv_b, (const unsigned short*)emb, hlf);
  k_transpose<<<4096, 256, 0, stream>>>(hlf, hfl);
  k_attn<<<256, 256, 0, stream>>>(ubf, hlf, hfl, fc_w, fc_b, out);
  k_loss<<<1, 256, 0, stream>>>(target, out);
}

// Round 2
// 334.178 us; speedup vs baseline: 1.2923x; 1.2923x over previous
//
#include <hip/hip_runtime.h>
#include <math.h>

using short8  = __attribute__((ext_vector_type(8))) short;
using floatx4 = __attribute__((ext_vector_type(4))) float;
using uintx4  = __attribute__((ext_vector_type(4))) unsigned int;
using uintx2  = __attribute__((ext_vector_type(2))) unsigned int;

__device__ __forceinline__ unsigned short f2bf(float f) {
  union { float f; unsigned int u; } v; v.f = f;
  unsigned int r = v.u + 0x7FFFu + ((v.u >> 16) & 1u);
  return (unsigned short)(r >> 16);
}
__device__ __forceinline__ float bf2f(unsigned short h) {
  union { unsigned int u; float f; } v; v.u = ((unsigned int)h) << 16;
  return v.f;
}

#define B_  16
#define L_  4096
#define E_  128
#define F_  256
#define Y_  1000

// workspace offsets (bytes)
#define OFF_HLF  0u          // B*L*F bf16 = 32 MB (l,f)
#define OFF_HFL  33554432u   // B*F*L bf16 = 32 MB (f,l)
#define OFF_UBF  67108864u   // 1024*256 bf16
#define OFF_PART 67633152u   // 512*128 float2 = 512 KB
#define OFF_LOSST 68157440u  // 16 floats

// ---------------- K0: repack U_w -> bf16, pad Y to 1024 ----------------
__global__ __launch_bounds__(256) void k_repack_u(const float* __restrict__ Uw,
                                                  unsigned short* __restrict__ ubf) {
  int i = blockIdx.x * 256 + threadIdx.x;
  int y = i >> 8, f = i & 255;
  float v = (y < Y_) ? Uw[y * F_ + f] : 0.f;
  ubf[i] = f2bf(v);
}

// ---------------- K1: fused embed-gather + conv1d(K=3,SAME) + bias + relu ----
// grid 1024: bid = nq(f-quarter) | b | lgroup(256 l). Waves partition f (16 each),
// W frags in registers. Epilogue LDS round-trip -> coalesced hlf AND hfl writes.
#define ET_STR 272   // 128 e * 2B + 16
#define TT_STR 144   // 64 * 2B + 16 (16B-aligned, 144%128=16 -> spread banks)
__global__ __launch_bounds__(256) void k_conv(const float* __restrict__ conv_w,
                                              const float* __restrict__ conv_b,
                                              const int* __restrict__ x,
                                              const float* __restrict__ ew,
                                              unsigned short* __restrict__ hlf,
                                              unsigned short* __restrict__ hfl) {
  __shared__ unsigned char lds[66 * ET_STR + 2 * 64 * TT_STR];  // 17952+18432=36384
  unsigned char* et = lds;                     // halo emb tile [66][128e]
  unsigned char* tl = lds + 66 * ET_STR;       // [l<64][f<64]
  unsigned char* tf = tl + 64 * TT_STR;        // [f<64][l<64]
  const int tid = threadIdx.x, bid = blockIdx.x;
  const int nq = bid & 3, grp = bid >> 2;
  const int b = grp >> 4, l0g = (grp & 15) << 8;
  const int w = tid >> 6, lane = tid & 63, c = lane & 15, q = lane >> 4;
  // W B-frags in regs: wave owns f-slice nq*64 + w*16
  const int fg = nq * 64 + w * 16 + c;
  short8 wf[3][4];
  #pragma unroll
  for (int d = 0; d < 3; ++d)
    #pragma unroll
    for (int kq = 0; kq < 4; ++kq) {
      short8 v;
      #pragma unroll
      for (int j = 0; j < 8; ++j)
        v[j] = (short)f2bf(conv_w[((size_t)fg * E_ + kq * 32 + q * 8 + j) * 3 + d]);
      wf[d][kq] = v;
    }
  const float bias = conv_b[fg];
  const int* xb = x + b * L_;
  for (int mt = 0; mt < 4; ++mt) {
    const int l0m = l0g + (mt << 6);
    // stage emb halo tile: gather+convert, rows l0m-1 .. l0m+64
    for (int s = tid; s < 66 * 32; s += 256) {
      int row = s >> 5, sg = s & 31;
      int l = l0m - 1 + row;
      uintx2 o = {0u, 0u};
      if (l >= 0 && l < L_) {
        int idx = xb[l];
        const float* src = ew + (size_t)idx * E_ + sg * 4;
        o.x = (unsigned int)f2bf(src[0]) | ((unsigned int)f2bf(src[1]) << 16);
        o.y = (unsigned int)f2bf(src[2]) | ((unsigned int)f2bf(src[3]) << 16);
      }
      *(uintx2*)(et + row * ET_STR + sg * 8) = o;
    }
    __syncthreads();
    floatx4 acc[4];
    #pragma unroll
    for (int ms = 0; ms < 4; ++ms) acc[ms] = (floatx4){0.f, 0.f, 0.f, 0.f};
    #pragma unroll
    for (int d = 0; d < 3; ++d)
      #pragma unroll
      for (int kq = 0; kq < 4; ++kq)
        #pragma unroll
        for (int ms = 0; ms < 4; ++ms) {
          short8 a = *(const short8*)(et + (ms * 16 + c + d) * ET_STR + kq * 64 + q * 16);
          acc[ms] = __builtin_amdgcn_mfma_f32_16x16x32_bf16(a, wf[d][kq], acc[ms], 0, 0, 0);
        }
    // epilogue: bias+relu, scatter into both LDS layouts
    const int fl = w * 16 + c;
    #pragma unroll
    for (int ms = 0; ms < 4; ++ms)
      #pragma unroll
      for (int r = 0; r < 4; ++r) {
        float v = acc[ms][r] + bias;
        v = v > 0.f ? v : 0.f;
        unsigned short h = f2bf(v);
        int ll = ms * 16 + q * 4 + r;
        *(unsigned short*)(tl + ll * TT_STR + fl * 2) = h;
        *(unsigned short*)(tf + fl * TT_STR + ll * 2) = h;
      }
    __syncthreads();
    // coalesced global stores, both layouts
    for (int s = tid; s < 512; s += 256) {
      int row = s >> 3, sg = s & 7;
      *(uintx4*)((unsigned char*)hlf + (((size_t)b * L_ + l0m + row) * F_ + nq * 64 + sg * 8) * 2) =
          *(const uintx4*)(tl + row * TT_STR + sg * 16);
    }
    for (int s = tid; s < 512; s += 256) {
      int fr = s >> 3, sg = s & 7;
      *(uintx4*)((unsigned char*)hfl + (((size_t)b * F_ + nq * 64 + fr) * L_ + l0m + sg * 8) * 2) =
          *(const uintx4*)(tf + fr * TT_STR + sg * 16);
    }
    __syncthreads();
  }
}

// ---------------- K2: label-wise attention, split-L partials ----------------
// grid 512 = 16b x 8yt(128y) x 4 chunks(1024 l). 2 wg/CU.
// GEMM1: wave = 32y x 64l (A=U regs). GEMM2: O^T (f,y), wave = 64f slice, B=P shared.
#define SHLF_STR 560   // 512+48 (48 mod 128 -> uniform bank spread)
#define SHFL_STR 176   // 128+48
#define SP_STR   176
__global__ __launch_bounds__(256, 2) void k_attn(const unsigned short* __restrict__ ubf,
                                                 const unsigned short* __restrict__ hlf,
                                                 const unsigned short* __restrict__ hfl,
                                                 const float* __restrict__ fcw,
                                                 float2* __restrict__ part) {
  __shared__ unsigned char lds[64 * SHLF_STR + 256 * SHFL_STR];  // 35840+45056=80896
  unsigned char* shlf = lds;                 // [l<64][f<256]
  unsigned char* shfl = lds + 64 * SHLF_STR; // [f<256][l<64]
  unsigned char* sP   = lds;                 // alias over shlf: [y<128][l<64]
  const int tid = threadIdx.x;
  const int w = tid >> 6, lane = tid & 63, c = lane & 15, q = lane >> 4;
  const int bid = blockIdx.x;
  const int xcd = bid & 7, r0 = bid >> 3;
  const int b = xcd * 2 + (r0 & 1);
  const int r2 = r0 >> 1, yt = r2 & 7, chunk = r2 >> 3;
  const int y0 = yt << 7;
  // U A-frags: 2 m-tiles x 8 k-steps
  short8 uf[2][8];
  #pragma unroll
  for (int mt = 0; mt < 2; ++mt)
    #pragma unroll
    for (int kq = 0; kq < 8; ++kq)
      uf[mt][kq] = *(const short8*)((const unsigned char*)ubf +
                     ((size_t)(y0 + w * 32 + mt * 16 + c) * F_ + kq * 32 + q * 8) * 2);
  floatx4 O[4][8];
  #pragma unroll
  for (int mt = 0; mt < 4; ++mt)
    #pragma unroll
    for (int nt = 0; nt < 8; ++nt) O[mt][nt] = (floatx4){0.f, 0.f, 0.f, 0.f};
  float Lacc[2][4] = {{0.f,0.f,0.f,0.f},{0.f,0.f,0.f,0.f}};
  const unsigned char* hlfb = (const unsigned char*)hlf + (size_t)b * L_ * (F_ * 2);
  const unsigned char* hflb = (const unsigned char*)hfl + (size_t)b * F_ * (L_ * 2);

  for (int it = 0; it < 16; ++it) {
    const int l0 = (chunk << 10) + (it << 6);
    for (int s = tid; s < 2048; s += 256) {        // stage H(l,f): 64 x 512B
      int row = s >> 5, sg = s & 31;
      *(uintx4*)(shlf + row * SHLF_STR + sg * 16) =
          *(const uintx4*)(hlfb + (size_t)(l0 + row) * (F_ * 2) + sg * 16);
    }
    for (int s = tid; s < 2048; s += 256) {        // stage H(f,l): 256 x 128B
      int f = s >> 3, sg = s & 7;
      *(uintx4*)(shfl + f * SHFL_STR + sg * 16) =
          *(const uintx4*)(hflb + (size_t)f * (L_ * 2) + l0 * 2 + sg * 16);
    }
    __syncthreads();
    // GEMM1: S[32y x 64l], K=256
    floatx4 S[2][4];
    #pragma unroll
    for (int mt = 0; mt < 2; ++mt)
      #pragma unroll
      for (int nt = 0; nt < 4; ++nt) S[mt][nt] = (floatx4){0.f, 0.f, 0.f, 0.f};
    #pragma unroll
    for (int kq = 0; kq < 8; ++kq)
      #pragma unroll
      for (int nt = 0; nt < 4; ++nt) {
        short8 bb = *(const short8*)(shlf + (nt * 16 + c) * SHLF_STR + kq * 64 + q * 16);
        S[0][nt] = __builtin_amdgcn_mfma_f32_16x16x32_bf16(uf[0][kq], bb, S[0][nt], 0, 0, 0);
        S[1][nt] = __builtin_amdgcn_mfma_f32_16x16x32_bf16(uf[1][kq], bb, S[1][nt], 0, 0, 0);
      }
    __syncthreads();   // shlf reads done; sP may overwrite
    // P = exp(S) -> sP[y][l]; accumulate La from bf16-rounded P (consistent with GEMM2)
    #pragma unroll
    for (int mt = 0; mt < 2; ++mt)
      #pragma unroll
      for (int nt = 0; nt < 4; ++nt)
        #pragma unroll
        for (int r = 0; r < 4; ++r) {
          float p = __expf(S[mt][nt][r]);
          unsigned short h = f2bf(p);
          *(unsigned short*)(sP + (w * 32 + mt * 16 + q * 4 + r) * SP_STR + (nt * 16 + c) * 2) = h;
          Lacc[mt][r] += bf2f(h);
        }
    __syncthreads();   // P visible to all waves
    // GEMM2: O^T[64f x 128y] += H^T x P, K=64. B=P cooperatively shared.
    #pragma unroll
    for (int kq = 0; kq < 2; ++kq) {
      short8 af[4];
      #pragma unroll
      for (int mt = 0; mt < 4; ++mt)
        af[mt] = *(const short8*)(shfl + (w * 64 + mt * 16 + c) * SHFL_STR + kq * 64 + q * 16);
      #pragma unroll
      for (int nt = 0; nt < 8; ++nt) {
        short8 bp = *(const short8*)(sP + (nt * 16 + c) * SP_STR + kq * 64 + q * 16);
        #pragma unroll
        for (int mt = 0; mt < 4; ++mt)
          O[mt][nt] = __builtin_amdgcn_mfma_f32_16x16x32_bf16(af[mt], bp, O[mt][nt], 0, 0, 0);
      }
    }
    __syncthreads();   // before restaging over shlf(sP)/shfl
  }
  // ---- epilogue ----
  // La: reduce over c lanes (l was spread across c via nt*16+c)
  #pragma unroll
  for (int mt = 0; mt < 2; ++mt)
    #pragma unroll
    for (int r = 0; r < 4; ++r) {
      float v = Lacc[mt][r];
      v += __shfl_xor(v, 1, 64); v += __shfl_xor(v, 2, 64);
      v += __shfl_xor(v, 4, 64); v += __shfl_xor(v, 8, 64);
      Lacc[mt][r] = v;
    }
  // num[y] partial over this wave's 64-f slice: O^T C-layout m=f(q*4+r,mt), n=y(c,nt)
  float num[8];
  #pragma unroll
  for (int nt = 0; nt < 8; ++nt) {
    int ya = y0 + nt * 16 + c;
    float s = 0.f;
    if (ya < Y_) {
      const float* fr = fcw + (size_t)ya * F_ + w * 64;
      #pragma unroll
      for (int mt = 0; mt < 4; ++mt)
        #pragma unroll
        for (int r = 0; r < 4; ++r)
          s += O[mt][nt][r] * fr[mt * 16 + q * 4 + r];
    }
    s += __shfl_xor(s, 16, 64); s += __shfl_xor(s, 32, 64);
    num[nt] = s;
  }
  float* sLa  = (float*)(lds + 64 * SHLF_STR);  // shfl region reuse
  float* sNum = sLa + 128;                      // [w][128]
  if (c == 0) {
    #pragma unroll
    for (int mt = 0; mt < 2; ++mt)
      #pragma unroll
      for (int r = 0; r < 4; ++r)
        sLa[w * 32 + mt * 16 + q * 4 + r] = Lacc[mt][r];
  }
  if (q == 0) {
    #pragma unroll
    for (int nt = 0; nt < 8; ++nt) sNum[w * 128 + nt * 16 + c] = num[nt];
  }
  __syncthreads();
  if (tid < 128) {
    float n4 = sNum[tid] + sNum[128 + tid] + sNum[256 + tid] + sNum[384 + tid];
    float2 v; v.x = n4; v.y = sLa[tid];
    part[(size_t)(((b * 8 + yt) * 4 + chunk)) * 128 + tid] = v;
  }
}

// ---------------- K3: combine partials -> logits + per-batch loss term ------
__global__ __launch_bounds__(256) void k_logits(const float2* __restrict__ part,
                                                const float* __restrict__ fcb,
                                                const int* __restrict__ target,
                                                float* __restrict__ out,
                                                float* __restrict__ losst) {
  __shared__ float red[4];
  const int b = blockIdx.x, tid = threadIdx.x;
  const int w = tid >> 6;
  float lg[4];
  #pragma unroll
  for (int k = 0; k < 4; ++k) {
    int y = tid + k * 256;
    int yt = y >> 7, yl = y & 127;
    float n = 0.f, la = 0.f;
    #pragma unroll
    for (int ch = 0; ch < 4; ++ch) {
      float2 v = part[(size_t)((b * 8 + yt) * 4 + ch) * 128 + yl];
      n += v.x; la += v.y;
    }
    float lv = (y < Y_) ? (n / la + fcb[y]) : -1e30f;
    lg[k] = lv;
    if (y < Y_) out[b * Y_ + y] = lv;
  }
  // block max
  float m = fmaxf(fmaxf(lg[0], lg[1]), fmaxf(lg[2], lg[3]));
  for (int off = 1; off < 64; off <<= 1) m = fmaxf(m, __shfl_xor(m, off, 64));
  if ((tid & 63) == 0) red[w] = m;
  __syncthreads();
  m = fmaxf(fmaxf(red[0], red[1]), fmaxf(red[2], red[3]));
  __syncthreads();
  // block sum of exp
  float s = 0.f;
  #pragma unroll
  for (int k = 0; k < 4; ++k)
    if (tid + k * 256 < Y_) s += __expf(lg[k] - m);
  for (int off = 1; off < 64; off <<= 1) s += __shfl_xor(s, off, 64);
  if ((tid & 63) == 0) red[w] = s;
  __syncthreads();
  s = red[0] + red[1] + red[2] + red[3];
  int t = target[b];
  #pragma unroll
  for (int k = 0; k < 4; ++k)
    if (tid + k * 256 == t) losst[b] = -(lg[k] - m - logf(s));
}

// ---------------- K4: mean of loss terms ----------------
__global__ __launch_bounds__(64) void k_sum(const float* __restrict__ losst,
                                            float* __restrict__ out) {
  int lane = threadIdx.x;
  float v = (lane < B_) ? losst[lane] : 0.f;
  v += __shfl_xor(v, 1, 64); v += __shfl_xor(v, 2, 64);
  v += __shfl_xor(v, 4, 64); v += __shfl_xor(v, 8, 64);
  if (lane == 0) out[B_ * Y_] = v * (1.f / (float)B_);
}

// ---------------- launcher ----------------
extern "C" void kernel_launch(void* const* d_in, const int* in_sizes, int n_in,
                              void* d_out, int out_size, void* d_ws, size_t ws_size,
                              hipStream_t stream) {
  const int*   x       = (const int*)d_in[0];
  const int*   target  = (const int*)d_in[1];
  const float* embed_w = (const float*)d_in[2];
  const float* conv_w  = (const float*)d_in[3];
  const float* conv_b  = (const float*)d_in[4];
  const float* U_w     = (const float*)d_in[5];
  const float* fc_w    = (const float*)d_in[6];
  const float* fc_b    = (const float*)d_in[7];
  float* out = (float*)d_out;
  unsigned char* ws = (unsigned char*)d_ws;
  unsigned short* hlf   = (unsigned short*)(ws + OFF_HLF);
  unsigned short* hfl   = (unsigned short*)(ws + OFF_HFL);
  unsigned short* ubf   = (unsigned short*)(ws + OFF_UBF);
  float2*         part  = (float2*)(ws + OFF_PART);
  float*          losst = (float*)(ws + OFF_LOSST);

  k_repack_u<<<1024, 256, 0, stream>>>(U_w, ubf);
  k_conv<<<1024, 256, 0, stream>>>(conv_w, conv_b, x, embed_w, hlf, hfl);
  k_attn<<<512, 256, 0, stream>>>(ubf, hlf, hfl, fc_w, part);
  k_logits<<<16, 256, 0, stream>>>(part, fc_b, target, out, losst);
  k_sum<<<1, 64, 0, stream>>>(losst, out);
}

// Round 3
// 240.196 us; speedup vs baseline: 1.7979x; 1.3913x over previous
//
#include <hip/hip_runtime.h>
#include <math.h>

using short8  = __attribute__((ext_vector_type(8))) short;
using floatx4 = __attribute__((ext_vector_type(4))) float;
using uintx4  = __attribute__((ext_vector_type(4))) unsigned int;
using uintx2  = __attribute__((ext_vector_type(2))) unsigned int;

#define AS1 __attribute__((address_space(1)))
#define AS3 __attribute__((address_space(3)))

__device__ __forceinline__ unsigned short f2bf(float f) {
  union { float f; unsigned int u; } v; v.f = f;
  unsigned int r = v.u + 0x7FFFu + ((v.u >> 16) & 1u);
  return (unsigned short)(r >> 16);
}
__device__ __forceinline__ float bf2f(unsigned short h) {
  union { unsigned int u; float f; } v; v.u = ((unsigned int)h) << 16;
  return v.f;
}
__device__ __forceinline__ void gload_lds16(const void* g, void* l) {
  __builtin_amdgcn_global_load_lds((const AS1 unsigned int*)g, (AS3 unsigned int*)l, 16, 0, 0);
}

#define B_  16
#define L_  4096
#define E_  128
#define F_  256
#define Y_  1000

// workspace offsets (bytes)
#define OFF_HLF   0u          // B*L*F bf16 = 32 MB (l,f)
#define OFF_HFL   33554432u   // B*F*L bf16 = 32 MB (f,l)
#define OFF_UBF   67108864u   // 1024*256 bf16
#define OFF_EBF   67633152u   // 50000*128 bf16 = 12.8 MB
#define OFF_WBF   80433152u   // 3*256*128 bf16 = 196608
#define OFF_PART  80629760u   // 512*128 float2 = 512 KB
#define OFF_LOSST 81154048u   // 16 floats

// ---------------- K0a: repack U_w -> bf16, pad Y to 1024 ----------------
__global__ __launch_bounds__(256) void k_repack_u(const float* __restrict__ Uw,
                                                  unsigned short* __restrict__ ubf) {
  int i = blockIdx.x * 256 + threadIdx.x;
  int y = i >> 8, f = i & 255;
  float v = (y < Y_) ? Uw[y * F_ + f] : 0.f;
  ubf[i] = f2bf(v);
}

// ---------------- K0b: repack embed table fp32 -> bf16 ----------------
__global__ __launch_bounds__(256) void k_repack_emb(const float* __restrict__ ew,
                                                    uintx4* __restrict__ ebf) {
  int i = blockIdx.x * 256 + threadIdx.x;   // 800000 = 50000*128/8
  const float4* s = (const float4*)ew + (size_t)i * 2;
  float4 a = s[0], b = s[1];
  uintx4 v;
  v.x = (unsigned int)f2bf(a.x) | ((unsigned int)f2bf(a.y) << 16);
  v.y = (unsigned int)f2bf(a.z) | ((unsigned int)f2bf(a.w) << 16);
  v.z = (unsigned int)f2bf(b.x) | ((unsigned int)f2bf(b.y) << 16);
  v.w = (unsigned int)f2bf(b.z) | ((unsigned int)f2bf(b.w) << 16);
  ebf[i] = v;
}

// ---------------- K0c: repack conv_w (F,E,K) -> bf16 [d][f][e] ----------------
__global__ __launch_bounds__(256) void k_repack_w(const float* __restrict__ cw,
                                                  unsigned short* __restrict__ wbf) {
  int i = blockIdx.x * 256 + threadIdx.x;   // 32768 = 256*128
  const float* s = cw + (size_t)i * 3;
  wbf[0 * 32768 + i] = f2bf(s[0]);
  wbf[1 * 32768 + i] = f2bf(s[1]);
  wbf[2 * 32768 + i] = f2bf(s[2]);
}

// ---------------- K1: fused embed-gather + conv1d(K=3,SAME) + bias + relu ----
// grid 1024 = 16b x 64 lgroups(64 l). wg does all 256 f via nq loop; emb staged once.
#define ET_STR 272
#define TT_STR 144
__global__ __launch_bounds__(256, 4) void k_conv(const unsigned short* __restrict__ wbf,
                                                 const float* __restrict__ conv_b,
                                                 const int* __restrict__ x,
                                                 const unsigned short* __restrict__ ebf,
                                                 unsigned short* __restrict__ hlf,
                                                 unsigned short* __restrict__ hfl) {
  __shared__ unsigned char lds[66 * ET_STR + 2 * 64 * TT_STR];  // 36384
  unsigned char* et = lds;
  unsigned char* tl = lds + 66 * ET_STR;
  unsigned char* tf = tl + 64 * TT_STR;
  const int tid = threadIdx.x, bid = blockIdx.x;
  const int b = bid >> 6, l0 = (bid & 63) << 6;
  const int w = tid >> 6, lane = tid & 63, c = lane & 15, q = lane >> 4;
  const int* xb = x + b * L_;
  // stage emb halo tile (66 rows x 256B bf16); OOB l -> vocab row 0 (zeros, padding_idx)
  for (int s = tid; s < 1056; s += 256) {
    int row = s >> 4, sg = s & 15;
    int l = l0 - 1 + row;
    int idx = (l >= 0 && l < L_) ? xb[l] : 0;
    uintx4 v = *(const uintx4*)((const unsigned char*)ebf + (size_t)idx * 256 + sg * 16);
    *(uintx4*)(et + row * ET_STR + sg * 16) = v;
  }
  __syncthreads();
  for (int nq = 0; nq < 4; ++nq) {
    const int fg = nq * 64 + w * 16 + c;
    short8 wf[3][4];
    #pragma unroll
    for (int d = 0; d < 3; ++d)
      #pragma unroll
      for (int kq = 0; kq < 4; ++kq)
        wf[d][kq] = *(const short8*)((const unsigned char*)wbf +
                      ((size_t)(d * F_ + fg) * E_ + kq * 32 + q * 8) * 2);
    const float bias = conv_b[fg];
    floatx4 acc[4];
    #pragma unroll
    for (int ms = 0; ms < 4; ++ms) acc[ms] = (floatx4){0.f, 0.f, 0.f, 0.f};
    #pragma unroll
    for (int d = 0; d < 3; ++d)
      #pragma unroll
      for (int kq = 0; kq < 4; ++kq)
        #pragma unroll
        for (int ms = 0; ms < 4; ++ms) {
          short8 a = *(const short8*)(et + (ms * 16 + c + d) * ET_STR + kq * 64 + q * 16);
          acc[ms] = __builtin_amdgcn_mfma_f32_16x16x32_bf16(a, wf[d][kq], acc[ms], 0, 0, 0);
        }
    const int fl = w * 16 + c;
    #pragma unroll
    for (int ms = 0; ms < 4; ++ms)
      #pragma unroll
      for (int r = 0; r < 4; ++r) {
        float v = acc[ms][r] + bias;
        v = v > 0.f ? v : 0.f;
        unsigned short h = f2bf(v);
        int ll = ms * 16 + q * 4 + r;
        *(unsigned short*)(tl + ll * TT_STR + fl * 2) = h;
        *(unsigned short*)(tf + fl * TT_STR + ll * 2) = h;
      }
    __syncthreads();
    for (int s = tid; s < 512; s += 256) {
      int row = s >> 3, sg = s & 7;
      *(uintx4*)((unsigned char*)hlf + (((size_t)b * L_ + l0 + row) * F_ + nq * 64 + sg * 8) * 2) =
          *(const uintx4*)(tl + row * TT_STR + sg * 16);
    }
    for (int s = tid; s < 512; s += 256) {
      int fr = s >> 3, sg = s & 7;
      *(uintx4*)((unsigned char*)hfl + (((size_t)b * F_ + nq * 64 + fr) * L_ + l0 + sg * 8) * 2) =
          *(const uintx4*)(tf + fr * TT_STR + sg * 16);
    }
    __syncthreads();
  }
}

// ---------------- K2: label-wise attention, split-L, gll + XOR-swizzle LDS ----
// grid 512 = 16b x 8yt(128y) x 4 chunks. 2 wg/CU. 3 barriers/iter.
// shlf: 64 l-rows x 512B (seg p holds global seg p^(row&7)); shfl: 256 f-rows x 128B.
// sP aliases shlf: [y<128][l<64] stride 184; wave-private rows -> no P barrier.
__global__ __launch_bounds__(256, 2) void k_attn(const unsigned short* __restrict__ ubf,
                                                 const unsigned short* __restrict__ hlf,
                                                 const unsigned short* __restrict__ hfl,
                                                 const float* __restrict__ fcw,
                                                 float2* __restrict__ part) {
  __shared__ unsigned char lds[65536];
  unsigned char* shlf = lds;
  unsigned char* shfl = lds + 32768;
  unsigned char* sP   = lds;   // alias over shlf (23552 B used)
  const int tid = threadIdx.x;
  const int w = tid >> 6, lane = tid & 63, c = lane & 15, q = lane >> 4;
  const int bid = blockIdx.x;
  const int xcd = bid & 7, r0 = bid >> 3;
  const int b = xcd * 2 + (r0 & 1);
  const int r2 = r0 >> 1, yt = r2 & 7, chunk = r2 >> 3;
  const int y0 = yt << 7;
  // U A-frags (2 m-tiles x 8 k-steps) resident
  short8 uf[2][8];
  #pragma unroll
  for (int mt = 0; mt < 2; ++mt)
    #pragma unroll
    for (int kq = 0; kq < 8; ++kq)
      uf[mt][kq] = *(const short8*)((const unsigned char*)ubf +
                     ((size_t)(y0 + w * 32 + mt * 16 + c) * F_ + kq * 32 + q * 8) * 2);
  floatx4 O[16][2];
  #pragma unroll
  for (int mt = 0; mt < 16; ++mt) {
    O[mt][0] = (floatx4){0.f, 0.f, 0.f, 0.f};
    O[mt][1] = (floatx4){0.f, 0.f, 0.f, 0.f};
  }
  float Lacc[2][4] = {{0.f,0.f,0.f,0.f},{0.f,0.f,0.f,0.f}};
  const unsigned char* hlfb = (const unsigned char*)hlf + (size_t)b * L_ * (F_ * 2);
  const unsigned char* hflb = (const unsigned char*)hfl + (size_t)b * F_ * (L_ * 2);
  // precomputed per-lane swizzled read offsets
  const int swz = c & 7;
  int boff[8], aoff[2];
  #pragma unroll
  for (int kq = 0; kq < 8; ++kq) boff[kq] = c * 512 + (((kq * 4 + q) ^ swz) << 4);
  #pragma unroll
  for (int kq = 0; kq < 2; ++kq) aoff[kq] = c * 128 + (((kq * 4 + q) ^ swz) << 4);
  const int pw_base = (w * 32 + q * 4) * 184 + c * 2;   // + mt*2944 + r*184 + nt*32
  const int pr_base = (w * 32 + c) * 184 + q * 16;      // + nt*2944 + kq*64

  for (int it = 0; it < 16; ++it) {
    const int l0 = (chunk << 10) + (it << 6);
    // stage H(l,f): 32 x 1KB gll, swizzled on global side
    #pragma unroll
    for (int ii = 0; ii < 8; ++ii) {
      int i = w * 8 + ii;
      int r = 2 * i + (lane >> 5);
      int g = (lane & 31) ^ (r & 7);
      gload_lds16(hlfb + (size_t)(l0 + r) * 512 + g * 16, shlf + i * 1024);
    }
    // stage H(f,l): 32 x 1KB gll
    #pragma unroll
    for (int ii = 0; ii < 8; ++ii) {
      int i = w * 8 + ii;
      int r = 8 * i + (lane >> 3);
      int g = (lane & 7) ^ (r & 7);
      gload_lds16(hflb + (size_t)r * (L_ * 2) + (size_t)l0 * 2 + g * 16, shfl + i * 1024);
    }
    __syncthreads();
    // GEMM1: S[32y x 64l], K=256
    floatx4 S[2][4];
    #pragma unroll
    for (int mt = 0; mt < 2; ++mt)
      #pragma unroll
      for (int nt = 0; nt < 4; ++nt) S[mt][nt] = (floatx4){0.f, 0.f, 0.f, 0.f};
    #pragma unroll
    for (int kq = 0; kq < 8; ++kq)
      #pragma unroll
      for (int nt = 0; nt < 4; ++nt) {
        short8 bb = *(const short8*)(shlf + nt * 8192 + boff[kq]);
        S[0][nt] = __builtin_amdgcn_mfma_f32_16x16x32_bf16(uf[0][kq], bb, S[0][nt], 0, 0, 0);
        S[1][nt] = __builtin_amdgcn_mfma_f32_16x16x32_bf16(uf[1][kq], bb, S[1][nt], 0, 0, 0);
      }
    __syncthreads();   // shlf reads done; sP (alias) may be written
    // P = exp(S) -> wave-private sP rows; La from bf16-rounded P
    #pragma unroll
    for (int mt = 0; mt < 2; ++mt)
      #pragma unroll
      for (int nt = 0; nt < 4; ++nt)
        #pragma unroll
        for (int r = 0; r < 4; ++r) {
          float p = __expf(S[mt][nt][r]);
          unsigned short h = f2bf(p);
          *(unsigned short*)(sP + pw_base + mt * 2944 + r * 184 + nt * 32) = h;
          Lacc[mt][r] += bf2f(h);
        }
    // GEMM2: O^T[256f x 32y] += H^T x P(own). lgkmcnt ordering is compiler-auto.
    #pragma unroll
    for (int kq = 0; kq < 2; ++kq) {
      short8 bp0 = *(const short8*)(sP + pr_base + 0 * 2944 + kq * 64);
      short8 bp1 = *(const short8*)(sP + pr_base + 1 * 2944 + kq * 64);
      #pragma unroll
      for (int mt = 0; mt < 16; ++mt) {
        short8 a = *(const short8*)(shfl + mt * 2048 + aoff[kq]);
        O[mt][0] = __builtin_amdgcn_mfma_f32_16x16x32_bf16(a, bp0, O[mt][0], 0, 0, 0);
        O[mt][1] = __builtin_amdgcn_mfma_f32_16x16x32_bf16(a, bp1, O[mt][1], 0, 0, 0);
      }
    }
    __syncthreads();   // before next stage overwrites shlf/sP/shfl
  }
  // ---- epilogue (wave-independent) ----
  // La reduce over c lanes (l spread via nt*16+c)
  #pragma unroll
  for (int mt = 0; mt < 2; ++mt)
    #pragma unroll
    for (int r = 0; r < 4; ++r) {
      float v = Lacc[mt][r];
      v += __shfl_xor(v, 1, 64); v += __shfl_xor(v, 2, 64);
      v += __shfl_xor(v, 4, 64); v += __shfl_xor(v, 8, 64);
      Lacc[mt][r] = v;
    }
  // num[y]: full 256-f dot in-wave; O^T C-layout m=f(mt,q*4+r), n=y(nt,c)
  float num[2];
  #pragma unroll
  for (int nt = 0; nt < 2; ++nt) {
    int ya = y0 + w * 32 + nt * 16 + c;
    float s = 0.f;
    if (ya < Y_) {
      const float* fr = fcw + (size_t)ya * F_;
      #pragma unroll
      for (int mt = 0; mt < 16; ++mt)
        #pragma unroll
        for (int r = 0; r < 4; ++r)
          s += O[mt][nt][r] * fr[mt * 16 + q * 4 + r];
    }
    s += __shfl_xor(s, 16, 64); s += __shfl_xor(s, 32, 64);
    num[nt] = s;
  }
  float2* pb = part + (size_t)((b * 8 + yt) * 4 + chunk) * 128;
  if (q == 0) {
    #pragma unroll
    for (int nt = 0; nt < 2; ++nt) pb[w * 32 + nt * 16 + c].x = num[nt];
  }
  if (c == 0) {
    #pragma unroll
    for (int mt = 0; mt < 2; ++mt)
      #pragma unroll
      for (int r = 0; r < 4; ++r) pb[w * 32 + mt * 16 + q * 4 + r].y = Lacc[mt][r];
  }
}

// ---------------- K3: combine partials -> logits + per-batch loss term ------
__global__ __launch_bounds__(256) void k_logits(const float2* __restrict__ part,
                                                const float* __restrict__ fcb,
                                                const int* __restrict__ target,
                                                float* __restrict__ out,
                                                float* __restrict__ losst) {
  __shared__ float red[4];
  const int b = blockIdx.x, tid = threadIdx.x;
  const int w = tid >> 6;
  float lg[4];
  #pragma unroll
  for (int k = 0; k < 4; ++k) {
    int y = tid + k * 256;
    int yt = y >> 7, yl = y & 127;
    float n = 0.f, la = 0.f;
    #pragma unroll
    for (int ch = 0; ch < 4; ++ch) {
      float2 v = part[(size_t)((b * 8 + yt) * 4 + ch) * 128 + yl];
      n += v.x; la += v.y;
    }
    float lv = (y < Y_) ? (n / la + fcb[y]) : -1e30f;
    lg[k] = lv;
    if (y < Y_) out[b * Y_ + y] = lv;
  }
  float m = fmaxf(fmaxf(lg[0], lg[1]), fmaxf(lg[2], lg[3]));
  for (int off = 1; off < 64; off <<= 1) m = fmaxf(m, __shfl_xor(m, off, 64));
  if ((tid & 63) == 0) red[w] = m;
  __syncthreads();
  m = fmaxf(fmaxf(red[0], red[1]), fmaxf(red[2], red[3]));
  __syncthreads();
  float s = 0.f;
  #pragma unroll
  for (int k = 0; k < 4; ++k)
    if (tid + k * 256 < Y_) s += __expf(lg[k] - m);
  for (int off = 1; off < 64; off <<= 1) s += __shfl_xor(s, off, 64);
  if ((tid & 63) == 0) red[w] = s;
  __syncthreads();
  s = red[0] + red[1] + red[2] + red[3];
  int t = target[b];
  #pragma unroll
  for (int k = 0; k < 4; ++k)
    if (tid + k * 256 == t) losst[b] = -(lg[k] - m - logf(s));
}

// ---------------- K4: mean of loss terms ----------------
__global__ __launch_bounds__(64) void k_sum(const float* __restrict__ losst,
                                            float* __restrict__ out) {
  int lane = threadIdx.x;
  float v = (lane < B_) ? losst[lane] : 0.f;
  v += __shfl_xor(v, 1, 64); v += __shfl_xor(v, 2, 64);
  v += __shfl_xor(v, 4, 64); v += __shfl_xor(v, 8, 64);
  if (lane == 0) out[B_ * Y_] = v * (1.f / (float)B_);
}

// ---------------- launcher ----------------
extern "C" void kernel_launch(void* const* d_in, const int* in_sizes, int n_in,
                              void* d_out, int out_size, void* d_ws, size_t ws_size,
                              hipStream_t stream) {
  const int*   x       = (const int*)d_in[0];
  const int*   target  = (const int*)d_in[1];
  const float* embed_w = (const float*)d_in[2];
  const float* conv_w  = (const float*)d_in[3];
  const float* conv_b  = (const float*)d_in[4];
  const float* U_w     = (const float*)d_in[5];
  const float* fc_w    = (const float*)d_in[6];
  const float* fc_b    = (const float*)d_in[7];
  float* out = (float*)d_out;
  unsigned char* ws = (unsigned char*)d_ws;
  unsigned short* hlf   = (unsigned short*)(ws + OFF_HLF);
  unsigned short* hfl   = (unsigned short*)(ws + OFF_HFL);
  unsigned short* ubf   = (unsigned short*)(ws + OFF_UBF);
  uintx4*         ebf   = (uintx4*)(ws + OFF_EBF);
  unsigned short* wbf   = (unsigned short*)(ws + OFF_WBF);
  float2*         part  = (float2*)(ws + OFF_PART);
  float*          losst = (float*)(ws + OFF_LOSST);

  k_repack_u<<<1024, 256, 0, stream>>>(U_w, ubf);
  k_repack_emb<<<3125, 256, 0, stream>>>(embed_w, ebf);
  k_repack_w<<<128, 256, 0, stream>>>(conv_w, wbf);
  k_conv<<<1024, 256, 0, stream>>>(wbf, conv_b, x, (const unsigned short*)ebf, hlf, hfl);
  k_attn<<<512, 256, 0, stream>>>(ubf, hlf, hfl, fc_w, part);
  k_logits<<<16, 256, 0, stream>>>(part, fc_b, target, out, losst);
  k_sum<<<1, 64, 0, stream>>>(losst, out);
}

// Round 4
// 198.418 us; speedup vs baseline: 2.1764x; 1.2106x over previous
//
#include <hip/hip_runtime.h>
#include <math.h>

using short8  = __attribute__((ext_vector_type(8))) short;
using floatx4 = __attribute__((ext_vector_type(4))) float;
using uintx4  = __attribute__((ext_vector_type(4))) unsigned int;
using uintx2  = __attribute__((ext_vector_type(2))) unsigned int;

#define AS1 __attribute__((address_space(1)))
#define AS3 __attribute__((address_space(3)))

__device__ __forceinline__ unsigned short f2bf(float f) {
  union { float f; unsigned int u; } v; v.f = f;
  unsigned int r = v.u + 0x7FFFu + ((v.u >> 16) & 1u);
  return (unsigned short)(r >> 16);
}
__device__ __forceinline__ float bf2f(unsigned short h) {
  union { unsigned int u; float f; } v; v.u = ((unsigned int)h) << 16;
  return v.f;
}
__device__ __forceinline__ void gload_lds16(const void* g, void* l) {
  __builtin_amdgcn_global_load_lds((const AS1 unsigned int*)g, (AS3 unsigned int*)l, 16, 0, 0);
}

#define B_  16
#define L_  4096
#define E_  128
#define F_  256
#define Y_  1000

// workspace offsets (bytes)
#define OFF_HLF   0u          // B*L*F bf16 = 32 MB (l,f)
#define OFF_HFL   33554432u   // B*F*L bf16 = 32 MB (f,l)
#define OFF_UBF   67108864u   // 1024*256 bf16 = 512 KB
#define OFF_WBF   67633152u   // 3*256*128 bf16 = 192 KB
#define OFF_PART  67829760u   // 512*128 float2 = 512 KB
#define OFF_LOSST 68354048u   // 16 floats

// ---------------- K0a: repack U_w -> bf16, pad Y to 1024 ----------------
__global__ __launch_bounds__(256) void k_repack_u(const float* __restrict__ Uw,
                                                  unsigned short* __restrict__ ubf) {
  int i = blockIdx.x * 256 + threadIdx.x;
  int y = i >> 8, f = i & 255;
  float v = (y < Y_) ? Uw[y * F_ + f] : 0.f;
  ubf[i] = f2bf(v);
}

// ---------------- K0b: repack conv_w (F,E,K) -> bf16 [d][f][e] ----------------
__global__ __launch_bounds__(256) void k_repack_w(const float* __restrict__ cw,
                                                  unsigned short* __restrict__ wbf) {
  int i = blockIdx.x * 256 + threadIdx.x;   // 32768 = 256*128
  const float* s = cw + (size_t)i * 3;
  wbf[0 * 32768 + i] = f2bf(s[0]);
  wbf[1 * 32768 + i] = f2bf(s[1]);
  wbf[2 * 32768 + i] = f2bf(s[2]);
}

// ---------------- K1: fused embed-gather(+fp32->bf16) + conv1d + bias + relu --
// grid 1024 = 16b x 64 lgroups(64 l). wg does all 256 f via nq loop.
#define ET_STR 272
#define TT_STR 144
__global__ __launch_bounds__(256, 4) void k_conv(const unsigned short* __restrict__ wbf,
                                                 const float* __restrict__ conv_b,
                                                 const int* __restrict__ x,
                                                 const float* __restrict__ ew,
                                                 unsigned short* __restrict__ hlf,
                                                 unsigned short* __restrict__ hfl) {
  __shared__ unsigned char lds[66 * ET_STR + 2 * 64 * TT_STR];  // 36384
  unsigned char* et = lds;
  unsigned char* tl = lds + 66 * ET_STR;
  unsigned char* tf = tl + 64 * TT_STR;
  const int tid = threadIdx.x, bid = blockIdx.x;
  const int b = bid >> 6, l0 = (bid & 63) << 6;
  const int w = tid >> 6, lane = tid & 63, c = lane & 15, q = lane >> 4;
  const int* xb = x + b * L_;
  // gather + convert emb halo tile (66 rows x 128e); OOB l -> row 0 (zeros)
  for (int s = tid; s < 1056; s += 256) {
    int row = s >> 4, sg = s & 15;
    int l = l0 - 1 + row;
    int idx = (l >= 0 && l < L_) ? xb[l] : 0;
    const float4* src = (const float4*)(ew + (size_t)idx * E_ + sg * 8);
    float4 a = src[0], bb = src[1];
    uintx4 v;
    v.x = (unsigned int)f2bf(a.x) | ((unsigned int)f2bf(a.y) << 16);
    v.y = (unsigned int)f2bf(a.z) | ((unsigned int)f2bf(a.w) << 16);
    v.z = (unsigned int)f2bf(bb.x) | ((unsigned int)f2bf(bb.y) << 16);
    v.w = (unsigned int)f2bf(bb.z) | ((unsigned int)f2bf(bb.w) << 16);
    *(uintx4*)(et + row * ET_STR + sg * 16) = v;
  }
  __syncthreads();
  for (int nq = 0; nq < 4; ++nq) {
    const int fg = nq * 64 + w * 16 + c;
    short8 wf[3][4];
    #pragma unroll
    for (int d = 0; d < 3; ++d)
      #pragma unroll
      for (int kq = 0; kq < 4; ++kq)
        wf[d][kq] = *(const short8*)((const unsigned char*)wbf +
                      ((size_t)(d * F_ + fg) * E_ + kq * 32 + q * 8) * 2);
    const float bias = conv_b[fg];
    floatx4 acc[4];
    #pragma unroll
    for (int ms = 0; ms < 4; ++ms) acc[ms] = (floatx4){0.f, 0.f, 0.f, 0.f};
    #pragma unroll
    for (int d = 0; d < 3; ++d)
      #pragma unroll
      for (int kq = 0; kq < 4; ++kq)
        #pragma unroll
        for (int ms = 0; ms < 4; ++ms) {
          short8 a = *(const short8*)(et + (ms * 16 + c + d) * ET_STR + kq * 64 + q * 16);
          acc[ms] = __builtin_amdgcn_mfma_f32_16x16x32_bf16(a, wf[d][kq], acc[ms], 0, 0, 0);
        }
    const int fl = w * 16 + c;
    #pragma unroll
    for (int ms = 0; ms < 4; ++ms)
      #pragma unroll
      for (int r = 0; r < 4; ++r) {
        float v = acc[ms][r] + bias;
        v = v > 0.f ? v : 0.f;
        unsigned short h = f2bf(v);
        int ll = ms * 16 + q * 4 + r;
        *(unsigned short*)(tl + ll * TT_STR + fl * 2) = h;
        *(unsigned short*)(tf + fl * TT_STR + ll * 2) = h;
      }
    __syncthreads();
    for (int s = tid; s < 512; s += 256) {
      int row = s >> 3, sg = s & 7;
      *(uintx4*)((unsigned char*)hlf + (((size_t)b * L_ + l0 + row) * F_ + nq * 64 + sg * 8) * 2) =
          *(const uintx4*)(tl + row * TT_STR + sg * 16);
    }
    for (int s = tid; s < 512; s += 256) {
      int fr = s >> 3, sg = s & 7;
      *(uintx4*)((unsigned char*)hfl + (((size_t)b * F_ + nq * 64 + fr) * L_ + l0 + sg * 8) * 2) =
          *(const uintx4*)(tf + fr * TT_STR + sg * 16);
    }
    __syncthreads();
  }
}

// ---------------- K2: label-wise attention, Tl=32 double-buffered pipeline ----
// grid 512 = 16b x 8yt(128y) x 4 chunks. 2 wg/CU. ONE barrier per iter:
// issue gll(tile i+1 -> idle buf) -> compute(tile i) -> barrier (vmcnt drain
// lands after full compute phase). sP dedicated (no alias, wave-private rows).
__global__ __launch_bounds__(256, 2) void k_attn(const unsigned short* __restrict__ ubf,
                                                 const unsigned short* __restrict__ hlf,
                                                 const unsigned short* __restrict__ hfl,
                                                 const float* __restrict__ fcw,
                                                 float2* __restrict__ part) {
  __shared__ unsigned char lds[75776];  // 2x(16K shlf + 16K shfl) + 128*80 sP
  unsigned char* sP = lds + 65536;
  const int tid = threadIdx.x;
  const int w = tid >> 6, lane = tid & 63, c = lane & 15, q = lane >> 4;
  const int bid = blockIdx.x;
  const int xcd = bid & 7, r0 = bid >> 3;
  const int b = xcd * 2 + (r0 & 1);
  const int r2 = r0 >> 1, yt = r2 & 7, chunk = r2 >> 3;
  const int y0 = yt << 7;
  // U A-frags (2 m-tiles x 8 k-steps) resident
  short8 uf[2][8];
  #pragma unroll
  for (int mt = 0; mt < 2; ++mt)
    #pragma unroll
    for (int kq = 0; kq < 8; ++kq)
      uf[mt][kq] = *(const short8*)((const unsigned char*)ubf +
                     ((size_t)(y0 + w * 32 + mt * 16 + c) * F_ + kq * 32 + q * 8) * 2);
  floatx4 O[16][2];
  #pragma unroll
  for (int mt = 0; mt < 16; ++mt) {
    O[mt][0] = (floatx4){0.f, 0.f, 0.f, 0.f};
    O[mt][1] = (floatx4){0.f, 0.f, 0.f, 0.f};
  }
  float Lacc[2][4] = {{0.f,0.f,0.f,0.f},{0.f,0.f,0.f,0.f}};
  const unsigned char* hlfb = (const unsigned char*)hlf + (size_t)b * L_ * (F_ * 2);
  const unsigned char* hflb = (const unsigned char*)hfl + (size_t)b * F_ * (L_ * 2);
  // swizzled read offsets
  int boff[8];
  #pragma unroll
  for (int kq = 0; kq < 8; ++kq) boff[kq] = c * 512 + (((kq * 4 + q) ^ (c & 7)) << 4);
  const int aoffc = c * 64 + ((q ^ (c & 3)) << 4);
  const int pw_base = (w * 32 + q * 4) * 80 + c * 2;   // + mt*1280 + r*80 + nt*32
  const int pr_base = (w * 32 + c) * 80 + q * 16;      // + nt2*1280
  // staging lane constants
  const int sl_r = lane >> 5, sl_g = lane & 31;   // shlf: 1KB = 2 rows x 512B
  const int sf_r = lane >> 2, sf_g = lane & 3;    // shfl: 1KB = 16 rows x 64B
  const int l0base = chunk << 10;

#define STAGE(dstbuf, l0v)                                                      \
  {                                                                             \
    unsigned char* dstb = (dstbuf);                                             \
    _Pragma("unroll")                                                           \
    for (int ii = 0; ii < 4; ++ii) {                                            \
      int i = w * 4 + ii;                                                       \
      int r = 2 * i + sl_r;                                                     \
      int g = sl_g ^ (r & 7);                                                   \
      gload_lds16(hlfb + (size_t)((l0v) + r) * 512 + g * 16, dstb + i * 1024);  \
    }                                                                           \
    _Pragma("unroll")                                                           \
    for (int ii = 0; ii < 4; ++ii) {                                            \
      int i = w * 4 + ii;                                                       \
      int r = 16 * i + sf_r;                                                    \
      int g = sf_g ^ (r & 3);                                                   \
      gload_lds16(hflb + (size_t)r * 8192 + (size_t)(l0v) * 2 + g * 16,         \
                  dstb + 16384 + i * 1024);                                     \
    }                                                                           \
  }

  STAGE(lds, l0base);
  __syncthreads();
  for (int it = 0; it < 32; ++it) {
    unsigned char* curb = lds + ((it & 1) << 15);
    if (it < 31) {
      unsigned char* nxtb = lds + (((it & 1) ^ 1) << 15);
      STAGE(nxtb, l0base + (it + 1) * 32);
    }
    unsigned char* shlf = curb;
    unsigned char* shfl = curb + 16384;
    // GEMM1: S[32y x 32l], K=256
    floatx4 S[2][2];
    S[0][0] = (floatx4){0.f,0.f,0.f,0.f}; S[0][1] = (floatx4){0.f,0.f,0.f,0.f};
    S[1][0] = (floatx4){0.f,0.f,0.f,0.f}; S[1][1] = (floatx4){0.f,0.f,0.f,0.f};
    #pragma unroll
    for (int kq = 0; kq < 8; ++kq)
      #pragma unroll
      for (int nt = 0; nt < 2; ++nt) {
        short8 bb = *(const short8*)(shlf + nt * 8192 + boff[kq]);
        S[0][nt] = __builtin_amdgcn_mfma_f32_16x16x32_bf16(uf[0][kq], bb, S[0][nt], 0, 0, 0);
        S[1][nt] = __builtin_amdgcn_mfma_f32_16x16x32_bf16(uf[1][kq], bb, S[1][nt], 0, 0, 0);
      }
    // P = exp(S) -> wave-private sP rows; La from bf16-rounded P
    #pragma unroll
    for (int mt = 0; mt < 2; ++mt)
      #pragma unroll
      for (int nt = 0; nt < 2; ++nt)
        #pragma unroll
        for (int r = 0; r < 4; ++r) {
          float p = __expf(S[mt][nt][r]);
          unsigned short h = f2bf(p);
          *(unsigned short*)(sP + pw_base + mt * 1280 + r * 80 + nt * 32) = h;
          Lacc[mt][r] += bf2f(h);
        }
    // GEMM2: O^T[256f x 32y] += H^T x P(own), K=32
    short8 bp0 = *(const short8*)(sP + pr_base);
    short8 bp1 = *(const short8*)(sP + pr_base + 1280);
    #pragma unroll
    for (int mt = 0; mt < 16; ++mt) {
      short8 a = *(const short8*)(shfl + mt * 1024 + aoffc);
      O[mt][0] = __builtin_amdgcn_mfma_f32_16x16x32_bf16(a, bp0, O[mt][0], 0, 0, 0);
      O[mt][1] = __builtin_amdgcn_mfma_f32_16x16x32_bf16(a, bp1, O[mt][1], 0, 0, 0);
    }
    __syncthreads();
  }
  // ---- epilogue (wave-independent) ----
  #pragma unroll
  for (int mt = 0; mt < 2; ++mt)
    #pragma unroll
    for (int r = 0; r < 4; ++r) {
      float v = Lacc[mt][r];
      v += __shfl_xor(v, 1, 64); v += __shfl_xor(v, 2, 64);
      v += __shfl_xor(v, 4, 64); v += __shfl_xor(v, 8, 64);
      Lacc[mt][r] = v;
    }
  float num[2];
  #pragma unroll
  for (int nt = 0; nt < 2; ++nt) {
    int ya = y0 + w * 32 + nt * 16 + c;
    float s = 0.f;
    if (ya < Y_) {
      const float* fr = fcw + (size_t)ya * F_;
      #pragma unroll
      for (int mt = 0; mt < 16; ++mt)
        #pragma unroll
        for (int r = 0; r < 4; ++r)
          s += O[mt][nt][r] * fr[mt * 16 + q * 4 + r];
    }
    s += __shfl_xor(s, 16, 64); s += __shfl_xor(s, 32, 64);
    num[nt] = s;
  }
  float2* pb = part + (size_t)((b * 8 + yt) * 4 + chunk) * 128;
  if (q == 0) {
    #pragma unroll
    for (int nt = 0; nt < 2; ++nt) pb[w * 32 + nt * 16 + c].x = num[nt];
  }
  if (c == 0) {
    #pragma unroll
    for (int mt = 0; mt < 2; ++mt)
      #pragma unroll
      for (int r = 0; r < 4; ++r) pb[w * 32 + mt * 16 + q * 4 + r].y = Lacc[mt][r];
  }
}

// ---------------- K3: combine partials -> logits + per-batch loss term ------
__global__ __launch_bounds__(256) void k_logits(const float2* __restrict__ part,
                                                const float* __restrict__ fcb,
                                                const int* __restrict__ target,
                                                float* __restrict__ out,
                                                float* __restrict__ losst) {
  __shared__ float red[4];
  const int b = blockIdx.x, tid = threadIdx.x;
  const int w = tid >> 6;
  float lg[4];
  #pragma unroll
  for (int k = 0; k < 4; ++k) {
    int y = tid + k * 256;
    int yt = y >> 7, yl = y & 127;
    float n = 0.f, la = 0.f;
    #pragma unroll
    for (int ch = 0; ch < 4; ++ch) {
      float2 v = part[(size_t)((b * 8 + yt) * 4 + ch) * 128 + yl];
      n += v.x; la += v.y;
    }
    float lv = (y < Y_) ? (n / la + fcb[y]) : -1e30f;
    lg[k] = lv;
    if (y < Y_) out[b * Y_ + y] = lv;
  }
  float m = fmaxf(fmaxf(lg[0], lg[1]), fmaxf(lg[2], lg[3]));
  for (int off = 1; off < 64; off <<= 1) m = fmaxf(m, __shfl_xor(m, off, 64));
  if ((tid & 63) == 0) red[w] = m;
  __syncthreads();
  m = fmaxf(fmaxf(red[0], red[1]), fmaxf(red[2], red[3]));
  __syncthreads();
  float s = 0.f;
  #pragma unroll
  for (int k = 0; k < 4; ++k)
    if (tid + k * 256 < Y_) s += __expf(lg[k] - m);
  for (int off = 1; off < 64; off <<= 1) s += __shfl_xor(s, off, 64);
  if ((tid & 63) == 0) red[w] = s;
  __syncthreads();
  s = red[0] + red[1] + red[2] + red[3];
  int t = target[b];
  #pragma unroll
  for (int k = 0; k < 4; ++k)
    if (tid + k * 256 == t) losst[b] = -(lg[k] - m - logf(s));
}

// ---------------- K4: mean of loss terms ----------------
__global__ __launch_bounds__(64) void k_sum(const float* __restrict__ losst,
                                            float* __restrict__ out) {
  int lane = threadIdx.x;
  float v = (lane < B_) ? losst[lane] : 0.f;
  v += __shfl_xor(v, 1, 64); v += __shfl_xor(v, 2, 64);
  v += __shfl_xor(v, 4, 64); v += __shfl_xor(v, 8, 64);
  if (lane == 0) out[B_ * Y_] = v * (1.f / (float)B_);
}

// ---------------- launcher ----------------
extern "C" void kernel_launch(void* const* d_in, const int* in_sizes, int n_in,
                              void* d_out, int out_size, void* d_ws, size_t ws_size,
                              hipStream_t stream) {
  const int*   x       = (const int*)d_in[0];
  const int*   target  = (const int*)d_in[1];
  const float* embed_w = (const float*)d_in[2];
  const float* conv_w  = (const float*)d_in[3];
  const float* conv_b  = (const float*)d_in[4];
  const float* U_w     = (const float*)d_in[5];
  const float* fc_w    = (const float*)d_in[6];
  const float* fc_b    = (const float*)d_in[7];
  float* out = (float*)d_out;
  unsigned char* ws = (unsigned char*)d_ws;
  unsigned short* hlf   = (unsigned short*)(ws + OFF_HLF);
  unsigned short* hfl   = (unsigned short*)(ws + OFF_HFL);
  unsigned short* ubf   = (unsigned short*)(ws + OFF_UBF);
  unsigned short* wbf   = (unsigned short*)(ws + OFF_WBF);
  float2*         part  = (float2*)(ws + OFF_PART);
  float*          losst = (float*)(ws + OFF_LOSST);

  k_repack_u<<<1024, 256, 0, stream>>>(U_w, ubf);
  k_repack_w<<<128, 256, 0, stream>>>(conv_w, wbf);
  k_conv<<<1024, 256, 0, stream>>>(wbf, conv_b, x, embed_w, hlf, hfl);
  k_attn<<<512, 256, 0, stream>>>(ubf, hlf, hfl, fc_w, part);
  k_logits<<<16, 256, 0, stream>>>(part, fc_b, target, out, losst);
  k_sum<<<1, 64, 0, stream>>>(losst, out);
}

// Round 5
// 185.744 us; speedup vs baseline: 2.3249x; 1.0682x over previous
//
#include <hip/hip_runtime.h>
#include <math.h>

using short8   = __attribute__((ext_vector_type(8)))  short;
using floatx4  = __attribute__((ext_vector_type(4)))  float;
using floatx16 = __attribute__((ext_vector_type(16))) float;
using uintx4   = __attribute__((ext_vector_type(4)))  unsigned int;

#define AS1 __attribute__((address_space(1)))
#define AS3 __attribute__((address_space(3)))

__device__ __forceinline__ unsigned short f2bf(float f) {
  union { float f; unsigned int u; } v; v.f = f;
  unsigned int r = v.u + 0x7FFFu + ((v.u >> 16) & 1u);
  return (unsigned short)(r >> 16);
}
__device__ __forceinline__ void gload_lds16(const void* g, void* l) {
  __builtin_amdgcn_global_load_lds((const AS1 unsigned int*)g, (AS3 unsigned int*)l, 16, 0, 0);
}

#define B_  16
#define L_  4096
#define E_  128
#define F_  256
#define Y_  1000

// workspace offsets (bytes)
#define OFF_HLF   0u          // B*L*F bf16 = 32 MB (l,f) rows of 512B
#define OFF_UBF   33554432u   // 1024*256 bf16 (U padded)
#define OFF_FBF   34078720u   // 1024*256 bf16 (fc_w padded)
#define OFF_WBF   34603008u   // 3*256*128 bf16
#define OFF_PART  34799616u   // 512*128 float2
#define OFF_LOSST 35323904u   // 16 floats

// ---------------- K0a: repack (Y,F) fp32 -> bf16, pad Y to 1024 (U_w, fc_w) --
__global__ __launch_bounds__(256) void k_repack_u(const float* __restrict__ src,
                                                  unsigned short* __restrict__ dst) {
  int i = blockIdx.x * 256 + threadIdx.x;
  int y = i >> 8, f = i & 255;
  float v = (y < Y_) ? src[y * F_ + f] : 0.f;
  dst[i] = f2bf(v);
}

// ---------------- K0b: repack conv_w (F,E,K) -> bf16 [d][f][e] ----------------
__global__ __launch_bounds__(256) void k_repack_w(const float* __restrict__ cw,
                                                  unsigned short* __restrict__ wbf) {
  int i = blockIdx.x * 256 + threadIdx.x;   // 32768 = 256*128
  const float* s = cw + (size_t)i * 3;
  wbf[0 * 32768 + i] = f2bf(s[0]);
  wbf[1 * 32768 + i] = f2bf(s[1]);
  wbf[2 * 32768 + i] = f2bf(s[2]);
}

// ---------------- K1: fused embed-gather + conv1d(K=3,SAME) + bias + relu ----
// grid 1024 = 16b x 64 lgroups(64 l). Wave owns 64 f; A-frags hoisted (et read
// once per (d,kq,ms)); B streamed from L2-resident wbf; direct b16 stores.
#define ET_STR 272
__global__ __launch_bounds__(256, 4) void k_conv(const unsigned short* __restrict__ wbf,
                                                 const float* __restrict__ conv_b,
                                                 const int* __restrict__ x,
                                                 const float* __restrict__ ew,
                                                 unsigned short* __restrict__ hlf) {
  __shared__ unsigned char et[66 * ET_STR];  // 17952
  const int tid = threadIdx.x, bid = blockIdx.x;
  const int b = bid >> 6, l0 = (bid & 63) << 6;
  const int w = tid >> 6, lane = tid & 63, c = lane & 15, q = lane >> 4;
  const int* xb = x + b * L_;
  // gather + fp32->bf16 convert emb halo tile (66 rows x 128 e)
  for (int s = tid; s < 1056; s += 256) {
    int row = s >> 4, sg = s & 15;
    int l = l0 - 1 + row;
    int idx = (l >= 0 && l < L_) ? xb[l] : 0;
    const float4* src = (const float4*)(ew + (size_t)idx * E_ + sg * 8);
    float4 a = src[0], bb = src[1];
    uintx4 v;
    v.x = (unsigned int)f2bf(a.x) | ((unsigned int)f2bf(a.y) << 16);
    v.y = (unsigned int)f2bf(a.z) | ((unsigned int)f2bf(a.w) << 16);
    v.z = (unsigned int)f2bf(bb.x) | ((unsigned int)f2bf(bb.y) << 16);
    v.w = (unsigned int)f2bf(bb.z) | ((unsigned int)f2bf(bb.w) << 16);
    *(uintx4*)(et + row * ET_STR + sg * 16) = v;
  }
  __syncthreads();
  const int fw = w * 64;
  floatx4 acc[4][4];
  #pragma unroll
  for (int ms = 0; ms < 4; ++ms)
    #pragma unroll
    for (int nt = 0; nt < 4; ++nt) acc[ms][nt] = (floatx4){0.f, 0.f, 0.f, 0.f};
  #pragma unroll
  for (int d = 0; d < 3; ++d)
    #pragma unroll
    for (int kq = 0; kq < 4; ++kq) {
      short8 aa[4], bb[4];
      #pragma unroll
      for (int ms = 0; ms < 4; ++ms)
        aa[ms] = *(const short8*)(et + (ms * 16 + q * 4 + (0) + c * 0 + 0 + (ms * 0)) * 0 +
                                  (ms * 16 + c + d) * ET_STR + kq * 64 + q * 16);
      #pragma unroll
      for (int nt = 0; nt < 4; ++nt)
        bb[nt] = *(const short8*)((const unsigned char*)wbf +
                   ((size_t)(d * F_ + fw + nt * 16 + c) * E_ + kq * 32 + q * 8) * 2);
      #pragma unroll
      for (int ms = 0; ms < 4; ++ms)
        #pragma unroll
        for (int nt = 0; nt < 4; ++nt)
          acc[ms][nt] = __builtin_amdgcn_mfma_f32_16x16x32_bf16(aa[ms], bb[nt], acc[ms][nt], 0, 0, 0);
    }
  // epilogue: bias + relu, direct b16 stores (C: col=f@c, row=l@q*4+r)
  #pragma unroll
  for (int nt = 0; nt < 4; ++nt) {
    int f = fw + nt * 16 + c;
    float bias = conv_b[f];
    #pragma unroll
    for (int ms = 0; ms < 4; ++ms)
      #pragma unroll
      for (int r = 0; r < 4; ++r) {
        int l = l0 + ms * 16 + q * 4 + r;
        float v = acc[ms][nt][r] + bias;
        v = v > 0.f ? v : 0.f;
        hlf[((size_t)b * L_ + l) * F_ + f] = f2bf(v);
      }
  }
}

// ---------------- K2: fused attention: S=U*H^T and G=Fc*H^T share B-frags ----
// logit num = sum_l exp(S)*G, den = sum_l exp(S). No GEMM2, no P, no hfl.
// grid 512 = 16b x 8yt(128y) x 4chunks(1024 l). 2 wg/CU. mfma_32x32x16.
// Wave = 32 y x 32 l per iter; dbuf 2x16KB; one barrier/iter.
__global__ __launch_bounds__(256, 2) void k_attn(const unsigned short* __restrict__ ubf,
                                                 const unsigned short* __restrict__ fbf,
                                                 const unsigned short* __restrict__ hlf,
                                                 float2* __restrict__ part) {
  __shared__ unsigned char lds[32768];
  const int tid = threadIdx.x;
  const int w = tid >> 6, lane = tid & 63, lo = lane & 31, hi = lane >> 5;
  const int bid = blockIdx.x;
  const int xcd = bid & 7, r0 = bid >> 3;
  const int b = xcd * 2 + (r0 & 1);
  const int r2 = r0 >> 1, yt = r2 & 7, chunk = r2 >> 3;
  const int y0 = yt << 7, yw = y0 + w * 32;
  // A-frags resident: U and Fc rows for wave's 32 y, K=256 -> 16 k-steps
  // A layout (32x32x16): m=lane&31, k=(lane>>5)*8 + j
  short8 uf[16], ff[16];
  #pragma unroll
  for (int ks = 0; ks < 16; ++ks) {
    size_t off = ((size_t)(yw + lo) * F_ + ks * 16 + hi * 8) * 2;
    uf[ks] = *(const short8*)((const unsigned char*)ubf + off);
    ff[ks] = *(const short8*)((const unsigned char*)fbf + off);
  }
  float num[16], den[16];
  #pragma unroll
  for (int r = 0; r < 16; ++r) { num[r] = 0.f; den[r] = 0.f; }
  const unsigned char* hlfb = (const unsigned char*)hlf + (size_t)b * L_ * (F_ * 2);
  const int l0base = chunk << 10;

  // stage: 16KB tile = 16 gll x 1KB (2 rows x 512B); XOR-swizzle granule by row
#define STAGE(dstbuf, l0v)                                                      \
  {                                                                             \
    unsigned char* dstb = (dstbuf);                                             \
    _Pragma("unroll")                                                           \
    for (int ii = 0; ii < 4; ++ii) {                                            \
      int i = w * 4 + ii;                                                       \
      int r = 2 * i + hi;                                                       \
      int g = lo ^ r;                                                           \
      gload_lds16(hlfb + (size_t)((l0v) + r) * 512 + g * 16, dstb + i * 1024);  \
    }                                                                           \
  }

  STAGE(lds, l0base);
  __syncthreads();
  for (int it = 0; it < 32; ++it) {
    unsigned char* cur = lds + ((it & 1) << 14);
    if (it < 31) STAGE(lds + (((it & 1) ^ 1) << 14), l0base + (it + 1) * 32);
    floatx16 S = {0.f,0.f,0.f,0.f,0.f,0.f,0.f,0.f,0.f,0.f,0.f,0.f,0.f,0.f,0.f,0.f};
    floatx16 G = {0.f,0.f,0.f,0.f,0.f,0.f,0.f,0.f,0.f,0.f,0.f,0.f,0.f,0.f,0.f,0.f};
    // B read: row(l)=lo, granule = (ks*2+hi)^lo  -> 8 consecutive lanes hit 8 banksets
    #pragma unroll
    for (int ks = 0; ks < 16; ++ks) {
      short8 bb = *(const short8*)(cur + lo * 512 + (((ks * 2 + hi) ^ lo) << 4));
      S = __builtin_amdgcn_mfma_f32_32x32x16_bf16(uf[ks], bb, S, 0, 0, 0);
      G = __builtin_amdgcn_mfma_f32_32x32x16_bf16(ff[ks], bb, G, 0, 0, 0);
    }
    #pragma unroll
    for (int r = 0; r < 16; ++r) {
      float p = __expf(S[r]);
      num[r] += p * G[r];
      den[r] += p;
    }
    __syncthreads();
  }
  // reduce over the 32 l-columns (lanes lo=0..31 within each hi-half)
  #pragma unroll
  for (int r = 0; r < 16; ++r) {
    float n = num[r], d = den[r];
    n += __shfl_xor(n, 1, 64);  d += __shfl_xor(d, 1, 64);
    n += __shfl_xor(n, 2, 64);  d += __shfl_xor(d, 2, 64);
    n += __shfl_xor(n, 4, 64);  d += __shfl_xor(d, 4, 64);
    n += __shfl_xor(n, 8, 64);  d += __shfl_xor(d, 8, 64);
    n += __shfl_xor(n, 16, 64); d += __shfl_xor(d, 16, 64);
    num[r] = n; den[r] = d;
  }
  float2* pb = part + (size_t)((b * 8 + yt) * 4 + chunk) * 128;
  if (lo == 0) {
    #pragma unroll
    for (int r = 0; r < 16; ++r) {
      int yl = w * 32 + (r & 3) + 8 * (r >> 2) + 4 * hi;  // C/D row mapping
      float2 v; v.x = num[r]; v.y = den[r];
      pb[yl] = v;
    }
  }
}

// ---------------- K3: combine partials -> logits + per-batch loss term ------
__global__ __launch_bounds__(256) void k_logits(const float2* __restrict__ part,
                                                const float* __restrict__ fcb,
                                                const int* __restrict__ target,
                                                float* __restrict__ out,
                                                float* __restrict__ losst) {
  __shared__ float red[4];
  const int b = blockIdx.x, tid = threadIdx.x;
  const int w = tid >> 6;
  float lg[4];
  #pragma unroll
  for (int k = 0; k < 4; ++k) {
    int y = tid + k * 256;
    int yt = y >> 7, yl = y & 127;
    float n = 0.f, la = 0.f;
    #pragma unroll
    for (int ch = 0; ch < 4; ++ch) {
      float2 v = part[(size_t)((b * 8 + yt) * 4 + ch) * 128 + yl];
      n += v.x; la += v.y;
    }
    float lv = (y < Y_) ? (n / la + fcb[y]) : -1e30f;
    lg[k] = lv;
    if (y < Y_) out[b * Y_ + y] = lv;
  }
  float m = fmaxf(fmaxf(lg[0], lg[1]), fmaxf(lg[2], lg[3]));
  for (int off = 1; off < 64; off <<= 1) m = fmaxf(m, __shfl_xor(m, off, 64));
  if ((tid & 63) == 0) red[w] = m;
  __syncthreads();
  m = fmaxf(fmaxf(red[0], red[1]), fmaxf(red[2], red[3]));
  __syncthreads();
  float s = 0.f;
  #pragma unroll
  for (int k = 0; k < 4; ++k)
    if (tid + k * 256 < Y_) s += __expf(lg[k] - m);
  for (int off = 1; off < 64; off <<= 1) s += __shfl_xor(s, off, 64);
  if ((tid & 63) == 0) red[w] = s;
  __syncthreads();
  s = red[0] + red[1] + red[2] + red[3];
  int t = target[b];
  #pragma unroll
  for (int k = 0; k < 4; ++k)
    if (tid + k * 256 == t) losst[b] = -(lg[k] - m - logf(s));
}

// ---------------- K4: mean of loss terms ----------------
__global__ __launch_bounds__(64) void k_sum(const float* __restrict__ losst,
                                            float* __restrict__ out) {
  int lane = threadIdx.x;
  float v = (lane < B_) ? losst[lane] : 0.f;
  v += __shfl_xor(v, 1, 64); v += __shfl_xor(v, 2, 64);
  v += __shfl_xor(v, 4, 64); v += __shfl_xor(v, 8, 64);
  if (lane == 0) out[B_ * Y_] = v * (1.f / (float)B_);
}

// ---------------- launcher ----------------
extern "C" void kernel_launch(void* const* d_in, const int* in_sizes, int n_in,
                              void* d_out, int out_size, void* d_ws, size_t ws_size,
                              hipStream_t stream) {
  const int*   x       = (const int*)d_in[0];
  const int*   target  = (const int*)d_in[1];
  const float* embed_w = (const float*)d_in[2];
  const float* conv_w  = (const float*)d_in[3];
  const float* conv_b  = (const float*)d_in[4];
  const float* U_w     = (const float*)d_in[5];
  const float* fc_w    = (const float*)d_in[6];
  const float* fc_b    = (const float*)d_in[7];
  float* out = (float*)d_out;
  unsigned char* ws = (unsigned char*)d_ws;
  unsigned short* hlf   = (unsigned short*)(ws + OFF_HLF);
  unsigned short* ubf   = (unsigned short*)(ws + OFF_UBF);
  unsigned short* fbf   = (unsigned short*)(ws + OFF_FBF);
  unsigned short* wbf   = (unsigned short*)(ws + OFF_WBF);
  float2*         part  = (float2*)(ws + OFF_PART);
  float*          losst = (float*)(ws + OFF_LOSST);

  k_repack_u<<<1024, 256, 0, stream>>>(U_w, ubf);
  k_repack_u<<<1024, 256, 0, stream>>>(fc_w, fbf);
  k_repack_w<<<128, 256, 0, stream>>>(conv_w, wbf);
  k_conv<<<1024, 256, 0, stream>>>(wbf, conv_b, x, embed_w, hlf);
  k_attn<<<512, 256, 0, stream>>>(ubf, fbf, hlf, part);
  k_logits<<<16, 256, 0, stream>>>(part, fc_b, target, out, losst);
  k_sum<<<1, 64, 0, stream>>>(losst, out);
}